// Round 1
// baseline (564.139 us; speedup 1.0000x reference)
//
#include <hip/hip_runtime.h>

// DMV inside algorithm (log-space, sum semiring), one block per batch item.
// Charts FR, FL, IR, IL live in LDS ([64][65] padded, f32). CR/CL are derived:
//   CR[h][s] = (s==h) ? 0 : FR[h][s] - stR_hc[h]   (same for left)
// Per width w: phase A computes IR/IL (attach), phase B computes FR/FL (stop).
// 8-lane groups own one DP cell each; online logsumexp + shfl_xor merge.

#define NEGV   -1000000000.0f
#define NMAX   64
#define LDS_S  65            // pad: 65 % 32 == 1 -> column walks hit distinct banks
#define GROUP  8
#define NGROUPS 32           // 256 / 8

__device__ __forceinline__ void lse_merge(float& m, float& s, float mo, float so) {
    float mn = fmaxf(m, mo);
    s = s * __expf(m - mn) + so * __expf(mo - mn);
    m = mn;
}

__device__ __forceinline__ void lse_acc(float& m, float& s, float x) {
    float mn = fmaxf(m, x);
    s = s * __expf(m - mn) + __expf(x - mn);
    m = mn;
}

__global__ __launch_bounds__(256, 2)
void dmv_inside_kernel(const int* __restrict__ tag,
                       const int* __restrict__ len_arr,
                       const float* __restrict__ root_param,
                       const float* __restrict__ trans_param,
                       const float* __restrict__ dec_param,
                       float* __restrict__ out)
{
    __shared__ float sFR[NMAX * LDS_S];
    __shared__ float sFL[NMAX * LDS_S];
    __shared__ float sIR[NMAX * LDS_S];
    __shared__ float sIL[NMAX * LDS_S];
    __shared__ float goR_nc_s[NMAX], goR_hc_s[NMAX];
    __shared__ float goL_nc_s[NMAX], goL_hc_s[NMAX];
    __shared__ float stR_hc_s[NMAX], stL_hc_s[NMAX];
    __shared__ float root_s[NMAX];
    __shared__ int   th_s[NMAX];

    const int b   = blockIdx.x;
    const int tid = threadIdx.x;
    const int nl  = len_arr[b];          // 32..64; output only depends on [0, nl)

    // ---- init charts to NEG, load per-position params ----
    for (int idx = tid; idx < NMAX * LDS_S; idx += 256) {
        sFR[idx] = NEGV; sFL[idx] = NEGV; sIR[idx] = NEGV; sIL[idx] = NEGV;
    }
    float stR_nc_r = 0.f, stL_nc_r = 0.f;
    if (tid < NMAX) {
        int t = tag[b * NMAX + tid];
        th_s[tid] = t;
        const float* d = dec_param + t * 8;   // [dir][val][dec]
        goL_nc_s[tid] = d[0];   // L, NC, GO
        stL_nc_r      = d[1];   // L, NC, STOP
        goL_hc_s[tid] = d[2];   // L, HC, GO
        stL_hc_s[tid] = d[3];   // L, HC, STOP
        goR_nc_s[tid] = d[4];   // R, NC, GO
        stR_nc_r      = d[5];   // R, NC, STOP
        goR_hc_s[tid] = d[6];   // R, HC, GO
        stR_hc_s[tid] = d[7];   // R, HC, STOP
        root_s[tid]   = root_param[t];
    }
    __syncthreads();
    if (tid < NMAX) {
        sFR[tid * LDS_S + tid] = stR_nc_r;   // CR diag = 0 -> FR diag = stR_nc
        sFL[tid * LDS_S + tid] = stL_nc_r;
    }
    __syncthreads();

    const int gid = tid >> 3;    // group id 0..31
    const int lg  = tid & 7;     // lane in group

    for (int w = 1; w < nl; ++w) {
        const int cd    = nl - w;      // cells per direction
        const int cells = 2 * cd;

        // ---- phase A: IR[h][e], IL[hl][m0] ----
        for (int ci = gid; ci < cells; ci += NGROUPS) {
            float m = NEGV, s = 0.0f;
            if (ci < cd) {
                const int h = ci, e = h + w;
                const float gnc   = goR_nc_s[h];
                const float ghc_m = goR_hc_s[h] - stR_hc_s[h];  // fold CR=FR-st
                const int rowh = h * LDS_S, rowe = e * LDS_S;
                for (int k = lg; k < w; k += GROUP) {
                    const int si = h + k;
                    float crgo = (k == 0) ? gnc : (sFR[rowh + si] + ghc_m);
                    lse_acc(m, s, crgo + sFL[rowe + si + 1]);
                }
                #pragma unroll
                for (int off = 1; off < GROUP; off <<= 1)
                    lse_merge(m, s, __shfl_xor(m, off, 64), __shfl_xor(s, off, 64));
                if (lg == 0) {
                    float tr = trans_param[(th_s[h] * NMAX + th_s[e]) * 2 + 1];
                    sIR[rowh + e] = tr + m + __logf(s);
                }
            } else {
                const int hl = w + (ci - cd), m0 = hl - w;
                const float gnc   = goL_nc_s[hl];
                const float ghc_m = goL_hc_s[hl] - stL_hc_s[hl];
                const int rowhl = hl * LDS_S, rowm0 = m0 * LDS_S;
                for (int k = lg; k < w; k += GROUP) {
                    const int si = hl - k;
                    float clgo = (k == 0) ? gnc : (sFL[rowhl + si] + ghc_m);
                    lse_acc(m, s, clgo + sFR[rowm0 + si - 1]);
                }
                #pragma unroll
                for (int off = 1; off < GROUP; off <<= 1)
                    lse_merge(m, s, __shfl_xor(m, off, 64), __shfl_xor(s, off, 64));
                if (lg == 0) {
                    float tr = trans_param[(th_s[hl] * NMAX + th_s[m0]) * 2 + 0];
                    sIL[rowhl + m0] = tr + m + __logf(s);
                }
            }
        }
        __syncthreads();

        // ---- phase B: FR[h][e], FL[hl][m0] ----
        for (int ci = gid; ci < cells; ci += NGROUPS) {
            float m = NEGV, s = 0.0f;
            if (ci < cd) {
                const int h = ci, e = h + w;
                const int rowh = h * LDS_S;
                for (int k = lg; k < w; k += GROUP) {
                    const int mi = h + k + 1;
                    lse_acc(m, s, sIR[rowh + mi] + sFR[mi * LDS_S + e]);
                }
                #pragma unroll
                for (int off = 1; off < GROUP; off <<= 1)
                    lse_merge(m, s, __shfl_xor(m, off, 64), __shfl_xor(s, off, 64));
                if (lg == 0)
                    sFR[rowh + e] = m + __logf(s) + stR_hc_s[h];
            } else {
                const int hl = w + (ci - cd), m0 = hl - w;
                const int rowhl = hl * LDS_S;
                for (int k = lg; k < w; k += GROUP) {
                    const int mi = hl - k - 1;
                    lse_acc(m, s, sIL[rowhl + mi] + sFL[mi * LDS_S + m0]);
                }
                #pragma unroll
                for (int off = 1; off < GROUP; off <<= 1)
                    lse_merge(m, s, __shfl_xor(m, off, 64), __shfl_xor(s, off, 64));
                if (lg == 0)
                    sFL[rowhl + m0] = m + __logf(s) + stL_hc_s[hl];
            }
        }
        __syncthreads();
    }

    // ---- final: out[b] = lse_i( root[i] + FL[i][0] + FR[i][last] ), i < nl ----
    if (tid < 64) {
        const int last = nl - 1;
        float x = (tid < nl)
                    ? (root_s[tid] + sFL[tid * LDS_S + 0] + sFR[tid * LDS_S + last])
                    : NEGV;
        float m = x, s = 1.0f;
        #pragma unroll
        for (int off = 1; off < 64; off <<= 1)
            lse_merge(m, s, __shfl_xor(m, off, 64), __shfl_xor(s, off, 64));
        if (tid == 0) out[b] = m + __logf(s);
    }
}

extern "C" void kernel_launch(void* const* d_in, const int* in_sizes, int n_in,
                              void* d_out, int out_size, void* d_ws, size_t ws_size,
                              hipStream_t stream) {
    // setup_inputs order: id_array, tag_array, len_array, root_param, trans_param, dec_param
    const int*   tag   = (const int*)d_in[1];
    const int*   len_a = (const int*)d_in[2];
    const float* root  = (const float*)d_in[3];
    const float* trans = (const float*)d_in[4];
    const float* dec   = (const float*)d_in[5];
    float* outp = (float*)d_out;
    const int B = in_sizes[2];   // 1024

    dmv_inside_kernel<<<B, 256, 0, stream>>>(tag, len_a, root, trans, dec, outp);
}

// Round 2
// 396.080 us; speedup vs baseline: 1.4243x; 1.4243x over previous
//
#include <hip/hip_runtime.h>

// DMV inside algorithm (log-space, sum semiring), one block per batch item.
// Charts FR, FL, IR, IL in LDS [64][69] f32 (stride 69: phase-A diagonal walks
// hit banks 6g+lg, phase-B column walks 6g+5lg -> <=3-way, mostly 2-way=free).
// CR/CL derived: CR[h][s] = (s==h) ? 0 : FR[h][s] - stR_hc[h].
// All values kept in log2 space (params pre-scaled by log2(e)) so LSE uses
// native v_exp_f32 / v_log_f32; converted back by *ln2 at the end.
// 512 threads = 64 groups of 8 -> 2 blocks/CU = 16 waves/CU.

#define NEGV    -1000000000.0f
#define NMAX    64
#define LDS_S   69
#define GROUP   8
#define BLOCK   512
#define NGROUPS (BLOCK / GROUP)   // 64

#if __has_builtin(__builtin_amdgcn_exp2f)
#define EXP2F(x) __builtin_amdgcn_exp2f(x)
#else
#define EXP2F(x) __expf((x) * 0.6931471805599453f)
#endif
#if __has_builtin(__builtin_amdgcn_logf)
#define LOG2F(x) __builtin_amdgcn_logf(x)
#else
#define LOG2F(x) (__logf(x) * 1.4426950408889634f)
#endif
#define LOG2E 1.4426950408889634f
#define LN2   0.6931471805599453f

__device__ __forceinline__ void lse_merge(float& m, float& s, float mo, float so) {
    float mn = fmaxf(m, mo);
    s = s * EXP2F(m - mn) + so * EXP2F(mo - mn);
    m = mn;
}

__device__ __forceinline__ void lse_acc(float& m, float& s, float x) {
    float mn = fmaxf(m, x);
    s = s * EXP2F(m - mn) + EXP2F(x - mn);
    m = mn;
}

__global__ __launch_bounds__(BLOCK, 4)
void dmv_inside_kernel(const int* __restrict__ tag,
                       const int* __restrict__ len_arr,
                       const float* __restrict__ root_param,
                       const float* __restrict__ trans_param,
                       const float* __restrict__ dec_param,
                       float* __restrict__ out)
{
    __shared__ float sFR[NMAX * LDS_S];
    __shared__ float sFL[NMAX * LDS_S];
    __shared__ float sIR[NMAX * LDS_S];
    __shared__ float sIL[NMAX * LDS_S];
    __shared__ float goR_nc_s[NMAX], goR_hcm_s[NMAX];   // hcm = (go_hc - st_hc)
    __shared__ float goL_nc_s[NMAX], goL_hcm_s[NMAX];
    __shared__ float stR_hc_s[NMAX], stL_hc_s[NMAX];
    __shared__ float root_s[NMAX];
    __shared__ int   th_s[NMAX];

    const int b   = blockIdx.x;
    const int tid = threadIdx.x;
    const int nl  = len_arr[b];          // 32..64; output only depends on [0, nl)

    // ---- load per-position params (log2-scaled), write diag. No chart init:
    // every chart read is provably of a previously-computed cell. ----
    if (tid < NMAX) {
        int t = tag[b * NMAX + tid];
        th_s[tid] = t;
        const float* d = dec_param + t * 8;          // [dir][val][dec]
        float goL_nc = d[0] * LOG2E, stL_nc = d[1] * LOG2E;
        float goL_hc = d[2] * LOG2E, stL_hc = d[3] * LOG2E;
        float goR_nc = d[4] * LOG2E, stR_nc = d[5] * LOG2E;
        float goR_hc = d[6] * LOG2E, stR_hc = d[7] * LOG2E;
        goL_nc_s[tid]  = goL_nc;
        goL_hcm_s[tid] = goL_hc - stL_hc;
        goR_nc_s[tid]  = goR_nc;
        goR_hcm_s[tid] = goR_hc - stR_hc;
        stL_hc_s[tid]  = stL_hc;
        stR_hc_s[tid]  = stR_hc;
        root_s[tid]    = root_param[t] * LOG2E;
        sFR[tid * LDS_S + tid] = stR_nc;   // CR diag = 0 -> FR diag = stR_nc
        sFL[tid * LDS_S + tid] = stL_nc;
    }
    __syncthreads();

    const int gid = tid >> 3;    // group id 0..63
    const int lg  = tid & 7;     // lane in group

    for (int w = 1; w < nl; ++w) {
        const int cd    = nl - w;
        const int cells = 2 * cd;

        // ---- phase A: IR[h][h+w], IL[hl][hl-w] ----
        for (int ci = gid; ci < cells; ci += NGROUPS) {
            float m0 = NEGV, s0 = 0.f, m1 = NEGV, s1 = 0.f;
            if (ci < cd) {
                const int h = ci, e = h + w;
                const float gnc = goR_nc_s[h];
                const float ghm = goR_hcm_s[h];
                const float* pF = sFR + h * LDS_S + h;       // [+k]
                const float* pL = sFL + e * LDS_S + h + 1;   // [+k]
                int k = lg;
                if (k < w) {
                    float cr = (k == 0) ? gnc : (pF[k] + ghm);
                    lse_acc(m0, s0, cr + pL[k]);
                    for (k += GROUP; k < w; k += 2 * GROUP) {
                        lse_acc(m1, s1, pF[k] + ghm + pL[k]);
                        int k2 = k + GROUP;
                        if (k2 < w) lse_acc(m0, s0, pF[k2] + ghm + pL[k2]);
                    }
                }
                lse_merge(m0, s0, m1, s1);
                #pragma unroll
                for (int off = 1; off < GROUP; off <<= 1)
                    lse_merge(m0, s0, __shfl_xor(m0, off, 64), __shfl_xor(s0, off, 64));
                if (lg == 0) {
                    float tr = trans_param[(th_s[h] * NMAX + th_s[e]) * 2 + 1] * LOG2E;
                    sIR[h * LDS_S + e] = tr + m0 + LOG2F(s0);
                }
            } else {
                const int hl = w + (ci - cd), mc = hl - w;
                const float gnc = goL_nc_s[hl];
                const float ghm = goL_hcm_s[hl];
                const float* pF = sFL + hl * LDS_S + hl;      // [-k]
                const float* pR = sFR + mc * LDS_S + hl - 1;  // [-k]
                int k = lg;
                if (k < w) {
                    float cl = (k == 0) ? gnc : (pF[-k] + ghm);
                    lse_acc(m0, s0, cl + pR[-k]);
                    for (k += GROUP; k < w; k += 2 * GROUP) {
                        lse_acc(m1, s1, pF[-k] + ghm + pR[-k]);
                        int k2 = k + GROUP;
                        if (k2 < w) lse_acc(m0, s0, pF[-k2] + ghm + pR[-k2]);
                    }
                }
                lse_merge(m0, s0, m1, s1);
                #pragma unroll
                for (int off = 1; off < GROUP; off <<= 1)
                    lse_merge(m0, s0, __shfl_xor(m0, off, 64), __shfl_xor(s0, off, 64));
                if (lg == 0) {
                    float tr = trans_param[(th_s[hl] * NMAX + th_s[mc]) * 2 + 0] * LOG2E;
                    sIL[hl * LDS_S + mc] = tr + m0 + LOG2F(s0);
                }
            }
        }
        __syncthreads();

        // ---- phase B: FR[h][h+w], FL[hl][hl-w] ----
        for (int ci = gid; ci < cells; ci += NGROUPS) {
            float m0 = NEGV, s0 = 0.f, m1 = NEGV, s1 = 0.f;
            if (ci < cd) {
                const int h = ci, e = h + w;
                const float* pI = sIR + h * LDS_S + h + 1;    // [+k]
                const float* pF = sFR + (h + 1) * LDS_S + e;  // [+k*LDS_S]
                int k = lg;
                if (k < w) {
                    lse_acc(m0, s0, pI[k] + pF[k * LDS_S]);
                    for (k += GROUP; k < w; k += 2 * GROUP) {
                        lse_acc(m1, s1, pI[k] + pF[k * LDS_S]);
                        int k2 = k + GROUP;
                        if (k2 < w) lse_acc(m0, s0, pI[k2] + pF[k2 * LDS_S]);
                    }
                }
                lse_merge(m0, s0, m1, s1);
                #pragma unroll
                for (int off = 1; off < GROUP; off <<= 1)
                    lse_merge(m0, s0, __shfl_xor(m0, off, 64), __shfl_xor(s0, off, 64));
                if (lg == 0)
                    sFR[h * LDS_S + e] = m0 + LOG2F(s0) + stR_hc_s[h];
            } else {
                const int hl = w + (ci - cd), mc = hl - w;
                const float* pI = sIL + hl * LDS_S + hl - 1;      // [-k]
                const float* pF = sFL + (hl - 1) * LDS_S + mc;    // [-k*LDS_S]
                int k = lg;
                if (k < w) {
                    lse_acc(m0, s0, pI[-k] + pF[-k * LDS_S]);
                    for (k += GROUP; k < w; k += 2 * GROUP) {
                        lse_acc(m1, s1, pI[-k] + pF[-k * LDS_S]);
                        int k2 = k + GROUP;
                        if (k2 < w) lse_acc(m0, s0, pI[-k2] + pF[-k2 * LDS_S]);
                    }
                }
                lse_merge(m0, s0, m1, s1);
                #pragma unroll
                for (int off = 1; off < GROUP; off <<= 1)
                    lse_merge(m0, s0, __shfl_xor(m0, off, 64), __shfl_xor(s0, off, 64));
                if (lg == 0)
                    sFL[hl * LDS_S + mc] = m0 + LOG2F(s0) + stL_hc_s[hl];
            }
        }
        __syncthreads();
    }

    // ---- final: out[b] = ln2 * lse2_i( root[i] + FL[i][0] + FR[i][last] ) ----
    if (tid < 64) {
        const int last = nl - 1;
        float x = (tid < nl)
                    ? (root_s[tid] + sFL[tid * LDS_S + 0] + sFR[tid * LDS_S + last])
                    : NEGV;
        float m = x, s = 1.0f;
        #pragma unroll
        for (int off = 1; off < 64; off <<= 1)
            lse_merge(m, s, __shfl_xor(m, off, 64), __shfl_xor(s, off, 64));
        if (tid == 0) out[b] = (m + LOG2F(s)) * LN2;
    }
}

extern "C" void kernel_launch(void* const* d_in, const int* in_sizes, int n_in,
                              void* d_out, int out_size, void* d_ws, size_t ws_size,
                              hipStream_t stream) {
    // setup_inputs order: id_array, tag_array, len_array, root_param, trans_param, dec_param
    const int*   tag   = (const int*)d_in[1];
    const int*   len_a = (const int*)d_in[2];
    const float* root  = (const float*)d_in[3];
    const float* trans = (const float*)d_in[4];
    const float* dec   = (const float*)d_in[5];
    float* outp = (float*)d_out;
    const int B = in_sizes[2];   // 1024

    dmv_inside_kernel<<<B, BLOCK, 0, stream>>>(tag, len_a, root, trans, dec, outp);
}

// Round 3
// 264.014 us; speedup vs baseline: 2.1368x; 1.5002x over previous
//
#include <hip/hip_runtime.h>

// DMV inside algorithm (log2-space, sum semiring), one block per batch item.
// Structural layout:
//  - IR (upper triangle, e>h) and IL (lower, e<h) share ONE LDS array sI.
//  - FR (upper) and FL (lower) share ONE array sF; the diagonal (width-0,
//    st*_nc) is a parameter array, selected in-register at kc==w-1.
//  - CR/CL derived: CR[h][s] = FR[h][s] - stR_hc[h] (folded into ghm).
//  => LDS ~38 KB -> 4 blocks/CU = 32 waves/CU (VGPR<=64 via launch_bounds).
//  - Phases A (attach -> I) and B (stop -> F) are FUSED: B(h,w) needs width-w
//    data only from its own group's A output (passed in register `ir`), so
//    ONE barrier per width w (63 total, was 126).
//  - Two-pass LSE: 8 register-cached elements/lane (fixed unrolled loop,
//    clamped addr, NEGV mask), fmax tree + 3x shfl_xor max, then INDEPENDENT
//    exp2s + add tree + 3x shfl_xor add. exp is off the dependent chain.
// 1024 threads = 128 groups of 8 -> all cells (<=126) in a single trip.

#define NEGV   -1000000000.0f
#define NMAX   64
#define LDS_S  69          // 69%32=5: row walks bank 6g+lg, col walks 5*lg -> <=2-way (free)
#define BLOCK  1024

#if __has_builtin(__builtin_amdgcn_exp2f)
#define EXP2F(x) __builtin_amdgcn_exp2f(x)
#else
#define EXP2F(x) __expf((x) * 0.6931471805599453f)
#endif
#if __has_builtin(__builtin_amdgcn_logf)
#define LOG2F(x) __builtin_amdgcn_logf(x)
#else
#define LOG2F(x) (__logf(x) * 1.4426950408889634f)
#endif
#define LOG2E 1.4426950408889634f
#define LN2   0.6931471805599453f

__device__ __forceinline__ void lse_merge(float& m, float& s, float mo, float so) {
    float mn = fmaxf(m, mo);
    s = s * EXP2F(m - mn) + so * EXP2F(mo - mn);
    m = mn;
}

// 8 elems/lane x 8 lanes two-pass logsumexp2; returns m + log2(s) to ALL lanes.
__device__ __forceinline__ float lse8(const float* x) {
    float m01 = fmaxf(x[0], x[1]), m23 = fmaxf(x[2], x[3]);
    float m45 = fmaxf(x[4], x[5]), m67 = fmaxf(x[6], x[7]);
    float m = fmaxf(fmaxf(m01, m23), fmaxf(m45, m67));
    m = fmaxf(m, __shfl_xor(m, 1, 64));
    m = fmaxf(m, __shfl_xor(m, 2, 64));
    m = fmaxf(m, __shfl_xor(m, 4, 64));
    float e0 = EXP2F(x[0] - m), e1 = EXP2F(x[1] - m);
    float e2 = EXP2F(x[2] - m), e3 = EXP2F(x[3] - m);
    float e4 = EXP2F(x[4] - m), e5 = EXP2F(x[5] - m);
    float e6 = EXP2F(x[6] - m), e7 = EXP2F(x[7] - m);
    float s = ((e0 + e1) + (e2 + e3)) + ((e4 + e5) + (e6 + e7));
    s += __shfl_xor(s, 1, 64);
    s += __shfl_xor(s, 2, 64);
    s += __shfl_xor(s, 4, 64);
    return m + LOG2F(s);
}

__global__ __launch_bounds__(BLOCK, 8)
void dmv_inside_kernel(const int* __restrict__ tag,
                       const int* __restrict__ len_arr,
                       const float* __restrict__ root_param,
                       const float* __restrict__ trans_param,
                       const float* __restrict__ dec_param,
                       float* __restrict__ out)
{
    __shared__ float sI[NMAX * LDS_S];     // IR upper / IL lower triangle
    __shared__ float sF[NMAX * LDS_S];     // FR upper / FL lower triangle
    __shared__ float goNC[2][NMAX];        // [0]=L, [1]=R (log2-scaled)
    __shared__ float goHM[2][NMAX];        // go_hc - st_hc
    __shared__ float stHC[2][NMAX];
    __shared__ float stNC[2][NMAX];        // the "diagonal" of F
    __shared__ float root_s[NMAX];
    __shared__ int   th_s[NMAX];

    const int b   = blockIdx.x;
    const int tid = threadIdx.x;
    const int nl  = len_arr[b];            // 32..64; output depends only on [0,nl)

    if (tid < NMAX) {
        int t = tag[b * NMAX + tid];
        th_s[tid] = t;
        const float* d = dec_param + t * 8;   // [dir][val][dec], L=0 R=1
        goNC[0][tid] = d[0] * LOG2E;
        stNC[0][tid] = d[1] * LOG2E;
        goHM[0][tid] = (d[2] - d[3]) * LOG2E;
        stHC[0][tid] = d[3] * LOG2E;
        goNC[1][tid] = d[4] * LOG2E;
        stNC[1][tid] = d[5] * LOG2E;
        goHM[1][tid] = (d[6] - d[7]) * LOG2E;
        stHC[1][tid] = d[7] * LOG2E;
        root_s[tid]  = root_param[t] * LOG2E;
    }
    __syncthreads();

    const int gid = tid >> 3;      // 0..127 — one DP cell per group
    const int lg  = tid & 7;

    for (int w = 1; w < nl; ++w) {
        const int cd    = nl - w;
        const int cells = 2 * cd;          // <= 126 < 128 groups: single trip
        if (gid < cells) {
            const bool isR = gid < cd;
            const int  sd  = isR ? 1 : 0;
            const int  dir = isR ? 1 : -1;
            const int  h   = isR ? gid : (w + gid - cd);
            const int  e   = h + dir * w;

            // ---- phase A: I[h][e] = tr + lse_k( C[h][h+dir*k] + go + F_other ) ----
            const float tr  = trans_param[(th_s[h] * NMAX + th_s[e]) * 2 + sd] * LOG2E;
            const float gnc = goNC[sd][h];
            const float ghm = goHM[sd][h];
            const float dcO = stNC[sd ^ 1][e];     // other-side diag F[e][e]
            const int   oF  = h * LDS_S + h;       // own F row, elem [dir*k]
            const int   oC  = e * LDS_S + h + dir; // other F row e, elem [dir*k]
            float x[8];
            #pragma unroll
            for (int j = 0; j < 8; ++j) {
                int  k    = lg + 8 * j;
                int  kc   = (k < w - 1) ? k : (w - 1);
                bool last = (kc == w - 1);
                float vF  = sF[oF + dir * kc];                 // width kc (>=1 when used)
                float vC  = last ? dcO : sF[oC + dir * kc];    // width w-1-kc; diag at kc=w-1
                float v   = ((k == 0) ? gnc : (vF + ghm)) + vC;
                x[j] = (k < w) ? v : NEGV;
            }
            const float ir = lse8(x) + tr;
            if (lg == 0) sI[h * LDS_S + e] = ir;

            // ---- phase B (fused): F[h][e] = lse_k( I[h][h+dir*(k+1)] + F[h+dir*(k+1)][e] ) + st_hc ----
            const float dcN = stNC[sd][e];         // own-side diag F[e][e]
            const float sth = stHC[sd][h];
            const int   oI  = h * LDS_S + h + dir;       // elem [dir*k]
            const int   oF2 = (h + dir) * LDS_S + e;     // elem [dir*k*LDS_S]
            float y[8];
            #pragma unroll
            for (int j = 0; j < 8; ++j) {
                int  k    = lg + 8 * j;
                int  kc   = (k < w - 1) ? k : (w - 1);
                bool last = (kc == w - 1);
                float v1  = last ? ir  : sI[oI + dir * kc];             // width kc+1
                float v2  = last ? dcN : sF[oF2 + dir * kc * LDS_S];    // width w-1-kc
                float v   = v1 + v2;
                y[j] = (k < w) ? v : NEGV;
            }
            const float f = lse8(y) + sth;
            if (lg == 0) sF[h * LDS_S + e] = f;
        }
        __syncthreads();
    }

    // ---- final: out[b] = ln2 * lse_i( root[i] + FL[i][0] + FR[i][last] ), i < nl ----
    if (tid < 64) {
        const int last = nl - 1;
        float fl0 = (tid == 0)    ? stNC[0][0]    : sF[tid * LDS_S + 0];
        float fre = (tid == last) ? stNC[1][last] : sF[tid * LDS_S + last];
        float xx  = (tid < nl) ? (root_s[tid] + fl0 + fre) : NEGV;
        float m = xx, s = 1.0f;
        #pragma unroll
        for (int off = 1; off < 64; off <<= 1)
            lse_merge(m, s, __shfl_xor(m, off, 64), __shfl_xor(s, off, 64));
        if (tid == 0) out[b] = (m + LOG2F(s)) * LN2;
    }
}

extern "C" void kernel_launch(void* const* d_in, const int* in_sizes, int n_in,
                              void* d_out, int out_size, void* d_ws, size_t ws_size,
                              hipStream_t stream) {
    // setup_inputs order: id_array, tag_array, len_array, root_param, trans_param, dec_param
    const int*   tag   = (const int*)d_in[1];
    const int*   len_a = (const int*)d_in[2];
    const float* root  = (const float*)d_in[3];
    const float* trans = (const float*)d_in[4];
    const float* dec   = (const float*)d_in[5];
    float* outp = (float*)d_out;
    const int B = in_sizes[2];   // 1024

    dmv_inside_kernel<<<B, BLOCK, 0, stream>>>(tag, len_a, root, trans, dec, outp);
}